// Round 24
// baseline (36.358 us; speedup 1.0000x reference)
//
#include <hip/hip_runtime.h>

#define CI 32
#define CO 32
#define PD 64
#define QDIM 1024
#define M_TOTAL (32*4096)
#define TILE_M 128                 // per WG: waves = (rg 0..1) x (ih 0..1)
#define NBLK (M_TOTAL/TILE_M)      // 1024 WGs
#define WG_THREADS 256
#define XLS 33                     // Xl[m][i]: 16-lane reads distinct banks + bcast
#define OLS 33                     // U.o[lane][r]: 2-way free

typedef float  f32x2  __attribute__((ext_vector_type(2)));
typedef float  f32x4  __attribute__((ext_vector_type(4)));
typedef __bf16 bf16x4 __attribute__((ext_vector_type(4)));
typedef __bf16 bf16x8 __attribute__((ext_vector_type(8)));

// ---- one-time: Wk -> wsG, 16x16x32 A-fragment-linear layout ----
// byte addr = i*4096 + qb*2048 + kh*1024 + g*256 + c*16  (g = lane>>4, c = lane&15)
// holding Wk[k = kh*32 + g*8 + j][q = i*32 + qb*16 + c] as bf16x8 over j.
__global__ __launch_bounds__(256)
void wk_pack16(const float* __restrict__ Wk, __bf16* __restrict__ wsG)
{
    __shared__ float tile[64][33];
    const int i  = blockIdx.x;          // 0..31
    const int q0 = i * 32;
    const int t  = threadIdx.x;
#pragma unroll
    for (int s = 0; s < 2; ++s) {
        const int idx = t + s * 256;
        const int k = idx >> 3, ch = idx & 7;
        f32x4 v = *(const f32x4*)(Wk + (size_t)k * QDIM + q0 + ch * 4);
        tile[k][ch*4+0] = v[0]; tile[k][ch*4+1] = v[1];
        tile[k][ch*4+2] = v[2]; tile[k][ch*4+3] = v[3];
    }
    __syncthreads();
    const int qq = t >> 3;              // 0..31
    const int g8 = t & 7;               // (kh,g)
    const int kh = g8 >> 2, g = g8 & 3;
    const int qb = qq >> 4, c = qq & 15;
    bf16x8 o;
#pragma unroll
    for (int j = 0; j < 8; ++j) o[j] = (__bf16)tile[kh*32 + g*8 + j][qq];
    *(bf16x8*)((char*)wsG + (size_t)i * 4096 + qb * 2048 + kh * 1024
               + g * 256 + c * 16) = o;
}

// PROVEN BEST (R22, 36.2us, absmax 0.0625) — restored verbatim after R23's
// immediate-consumption variant (semantically identical step!) failed
// correctness at absmax 4.8: strong evidence of a compiler scheduling/hazard
// issue with narrowed MFMA C live-ranges. DO NOT narrow the C-tile live-range
// (R23 miscompile). DO NOT: min-waves>=4 (R7/R16 spill), per-lane X global
// rows (R18 scatter), scalar Wk gathers in-loop (R6), LDS-A 1WG/CU (R21).
__global__ __launch_bounds__(WG_THREADS, 2)
void cond_dense_kernel(const float* __restrict__ Xg, const float* __restrict__ Pg,
                       const __bf16* __restrict__ wsG, float* __restrict__ outg)
{
    __shared__ union {
        __bf16 p[TILE_M * PD];       // 16384 B: P-tile (dead after bfr)
        float  o[2 * 64 * OLS];      // 16896 B: partial-sum exchange
    } U;
    __shared__ float Xl[TILE_M * XLS];   // 16896 B: X row-major [m][i]

    const int t   = threadIdx.x;
    const int l   = t & 63;
    const int w   = t >> 6;
    const int rg  = w & 1;          // row-group: rows rg*64 .. rg*64+63
    const int ih  = w >> 1;         // i-half: i in ih*16 .. ih*16+15
    const int c16 = l & 15;         // MFMA col (m mod 16)
    const int h4  = l >> 4;         // 0..3: k-octet / D-row group
    const int tile0 = blockIdx.x * TILE_M;
    const int mbase = rg * 64;

    // ---- stage: P[128][64] -> bf16 swizzled; X[128][32] -> Xl[m][i] ----
    {
        const float* Pb = Pg + (size_t)tile0 * PD;
#pragma unroll
        for (int s = 0; s < 8; ++s) {
            const int id = t + 256 * s;
            const int r = id >> 4, ch = id & 15;
            f32x4 v = *(const f32x4*)(Pb + (size_t)r * PD + ch * 4);
            bf16x4 bv;
#pragma unroll
            for (int j = 0; j < 4; ++j) bv[j] = (__bf16)v[j];
            char* dst = (char*)U.p + r * 128
                      + ((((ch >> 1) ^ (r & 7)) << 4) | ((ch & 1) * 8));
            *(bf16x4*)dst = bv;
        }
        const float* Xb = Xg + (size_t)tile0 * CI;
#pragma unroll
        for (int s = 0; s < 4; ++s) {
            const int id = t + 256 * s;
            const int r = id >> 3, ch = id & 7;
            f32x4 v = *(const f32x4*)(Xb + (size_t)r * CI + ch * 4);
#pragma unroll
            for (int j = 0; j < 4; ++j) Xl[r * XLS + ch * 4 + j] = v[j];
        }
    }
    __syncthreads();

    // ---- B fragments (P^T) for 4 m-quarters x 2 k-halves ----
    // B[k][m]: lane col m = mbase+mq*16+c16, k = kh*32 + h4*8 + j
    bf16x8 bfr[4][2];
#pragma unroll
    for (int mq = 0; mq < 4; ++mq) {
        const int row = mbase + mq * 16 + c16;
#pragma unroll
        for (int kh = 0; kh < 2; ++kh) {
            const int g = ((h4 + 4 * kh) ^ (row & 7)) << 4;
            bfr[mq][kh] = *(const bf16x8*)((const char*)U.p + row * 128 + g);
        }
    }

    // ---- i-loop over this wave's half: 16 steps, next-i prefetch ----
    f32x2 oacc[16] = {};   // [qb*8 + mq*2 + p]: 32 f32
    const char* abase = (const char*)wsG + (size_t)(ih * 16) * 4096
                      + h4 * 256 + c16 * 16;
    const float* xb = &Xl[(mbase + c16) * XLS + ih * 16];  // + mq*16*XLS

    bf16x8 aq[4], an[4];   // [qb*2+kh] current / next
    auto aload = [&](int il, bf16x8* buf) {
        const char* p = abase + (size_t)il * 4096;
        buf[0] = *(const bf16x8*)(p);           // qb0 kh0
        buf[1] = *(const bf16x8*)(p + 1024);    // qb0 kh1
        buf[2] = *(const bf16x8*)(p + 2048);    // qb1 kh0
        buf[3] = *(const bf16x8*)(p + 3072);    // qb1 kh1
    };
    const f32x2 zero2 = {0.0f, 0.0f};
    auto step = [&](const bf16x8* a, int il) {
        f32x2 x2[4];
#pragma unroll
        for (int mq = 0; mq < 4; ++mq) {
            const float x = xb[mq * 16 * XLS + il];
            x2[mq][0] = x; x2[mq][1] = x;
        }
#pragma unroll
        for (int qb = 0; qb < 2; ++qb) {
            f32x4 cc[4] = {};                    // 8 chains of depth 2 per i
#pragma unroll
            for (int mq = 0; mq < 4; ++mq) {
                cc[mq] = __builtin_amdgcn_mfma_f32_16x16x32_bf16(a[qb*2+0], bfr[mq][0], cc[mq], 0, 0, 0);
                cc[mq] = __builtin_amdgcn_mfma_f32_16x16x32_bf16(a[qb*2+1], bfr[mq][1], cc[mq], 0, 0, 0);
            }
#pragma unroll
            for (int mq = 0; mq < 4; ++mq) {
#pragma unroll
                for (int p = 0; p < 2; ++p) {
                    f32x2 pr = {cc[mq][2*p], cc[mq][2*p + 1]};
                    oacc[qb*8 + mq*2 + p] +=
                        __builtin_elementwise_max(pr, zero2) * x2[mq];
                }
            }
        }
    };

    aload(0, aq);
    aload(1, an);
#pragma unroll
    for (int ii = 0; ii < 8; ++ii) {
        step(aq, 2 * ii);
        if (ii < 7) aload(2 * ii + 2, aq);
        step(an, 2 * ii + 1);
        if (ii < 7) aload(2 * ii + 3, an);
    }

    // ---- combine partials: ih=1 publishes, ih=0 adds and stores ----
    __syncthreads();                   // bfr reads long done; U.p -> U.o
    const int ob = (rg * 64 + l) * OLS;
    if (ih == 1) {
#pragma unroll
        for (int r = 0; r < 16; ++r)
            *(f32x2*)&U.o[ob + 2*r] = oacc[r];
    }
    __syncthreads();
    if (ih == 0) {
#pragma unroll
        for (int r = 0; r < 16; ++r)
            oacc[r] += *(const f32x2*)&U.o[ob + 2*r];
        // direct stores: lane (h4,c16): row m = mbase+mq*16+c16, col qb*16+h4*4
#pragma unroll
        for (int qb = 0; qb < 2; ++qb) {
#pragma unroll
            for (int mq = 0; mq < 4; ++mq) {
                f32x4 v;
                v[0] = oacc[qb*8 + mq*2 + 0][0];
                v[1] = oacc[qb*8 + mq*2 + 0][1];
                v[2] = oacc[qb*8 + mq*2 + 1][0];
                v[3] = oacc[qb*8 + mq*2 + 1][1];
                float* orow = outg + (size_t)(tile0 + mbase + mq*16 + c16) * CO
                            + qb * 16 + h4 * 4;
                *(f32x4*)orow = v;
            }
        }
    }
}

extern "C" void kernel_launch(void* const* d_in, const int* in_sizes, int n_in,
                              void* d_out, int out_size, void* d_ws, size_t ws_size,
                              hipStream_t stream)
{
    const float* X  = (const float*)d_in[0];
    const float* P  = (const float*)d_in[1];
    const float* Wk = (const float*)d_in[2];
    float* out  = (float*)d_out;
    __bf16* wsG = (__bf16*)d_ws;   // 32*4096 B = 128 KB

    wk_pack16<<<dim3(CI), dim3(256), 0, stream>>>(Wk, wsG);
    cond_dense_kernel<<<dim3(NBLK), dim3(WG_THREADS), 0, stream>>>(X, P, wsG, out);
}

// Round 25
// 35.972 us; speedup vs baseline: 1.0107x; 1.0107x over previous
//
#include <hip/hip_runtime.h>

#define CI 32
#define CO 32
#define PD 64
#define QDIM 1024
#define M_TOTAL (32*4096)
#define TILE_M 128                 // per WG: waves = (rg 0..1) x (ih 0..1)
#define NBLK (M_TOTAL/TILE_M)      // 1024 WGs
#define WG_THREADS 256
#define XLS 33                     // Xl[m][i]: 16-lane reads distinct banks + bcast
#define OLS 33                     // U.o[lane][r]: 2-way free

typedef float  f32x2  __attribute__((ext_vector_type(2)));
typedef float  f32x4  __attribute__((ext_vector_type(4)));
typedef __bf16 bf16x4 __attribute__((ext_vector_type(4)));
typedef __bf16 bf16x8 __attribute__((ext_vector_type(8)));

// ---- one-time: Wk -> wsG, 16x16x32 A-fragment-linear layout ----
// byte addr = i*4096 + qb*2048 + kh*1024 + g*256 + c*16  (g = lane>>4, c = lane&15)
// holding Wk[k = kh*32 + g*8 + j][q = i*32 + qb*16 + c] as bf16x8 over j.
__global__ __launch_bounds__(256)
void wk_pack16(const float* __restrict__ Wk, __bf16* __restrict__ wsG)
{
    __shared__ float tile[64][33];
    const int i  = blockIdx.x;          // 0..31
    const int q0 = i * 32;
    const int t  = threadIdx.x;
#pragma unroll
    for (int s = 0; s < 2; ++s) {
        const int idx = t + s * 256;
        const int k = idx >> 3, ch = idx & 7;
        f32x4 v = *(const f32x4*)(Wk + (size_t)k * QDIM + q0 + ch * 4);
        tile[k][ch*4+0] = v[0]; tile[k][ch*4+1] = v[1];
        tile[k][ch*4+2] = v[2]; tile[k][ch*4+3] = v[3];
    }
    __syncthreads();
    const int qq = t >> 3;              // 0..31
    const int g8 = t & 7;               // (kh,g)
    const int kh = g8 >> 2, g = g8 & 3;
    const int qb = qq >> 4, c = qq & 15;
    bf16x8 o;
#pragma unroll
    for (int j = 0; j < 8; ++j) o[j] = (__bf16)tile[kh*32 + g*8 + j][qq];
    *(bf16x8*)((char*)wsG + (size_t)i * 4096 + qb * 2048 + kh * 1024
               + g * 256 + c * 16) = o;
}

// R24 (proven best, 36.4us) with ONE token changed: launch_bounds min-waves
// 2 -> 3. Tests the hidden-AGPR residency theory safely: (256,3) asks the
// allocator for total V+A <= ~170 without restructuring the step (R23's
// restructure miscompiled — absmax 4.8 with semantically identical math).
// Risk ladder: (256,2) clean, (256,4) spill disaster (R16); midpoint untested.
// DO NOT: narrow C live-range (R23 miscompile), min-waves>=4 (R7/R16 spill),
// per-lane X global rows (R18), scalar Wk gathers in-loop (R6).
__global__ __launch_bounds__(WG_THREADS, 3)
void cond_dense_kernel(const float* __restrict__ Xg, const float* __restrict__ Pg,
                       const __bf16* __restrict__ wsG, float* __restrict__ outg)
{
    __shared__ union {
        __bf16 p[TILE_M * PD];       // 16384 B: P-tile (dead after bfr)
        float  o[2 * 64 * OLS];      // 16896 B: partial-sum exchange
    } U;
    __shared__ float Xl[TILE_M * XLS];   // 16896 B: X row-major [m][i]

    const int t   = threadIdx.x;
    const int l   = t & 63;
    const int w   = t >> 6;
    const int rg  = w & 1;          // row-group: rows rg*64 .. rg*64+63
    const int ih  = w >> 1;         // i-half: i in ih*16 .. ih*16+15
    const int c16 = l & 15;         // MFMA col (m mod 16)
    const int h4  = l >> 4;         // 0..3: k-octet / D-row group
    const int tile0 = blockIdx.x * TILE_M;
    const int mbase = rg * 64;

    // ---- stage: P[128][64] -> bf16 swizzled; X[128][32] -> Xl[m][i] ----
    {
        const float* Pb = Pg + (size_t)tile0 * PD;
#pragma unroll
        for (int s = 0; s < 8; ++s) {
            const int id = t + 256 * s;
            const int r = id >> 4, ch = id & 15;
            f32x4 v = *(const f32x4*)(Pb + (size_t)r * PD + ch * 4);
            bf16x4 bv;
#pragma unroll
            for (int j = 0; j < 4; ++j) bv[j] = (__bf16)v[j];
            char* dst = (char*)U.p + r * 128
                      + ((((ch >> 1) ^ (r & 7)) << 4) | ((ch & 1) * 8));
            *(bf16x4*)dst = bv;
        }
        const float* Xb = Xg + (size_t)tile0 * CI;
#pragma unroll
        for (int s = 0; s < 4; ++s) {
            const int id = t + 256 * s;
            const int r = id >> 3, ch = id & 7;
            f32x4 v = *(const f32x4*)(Xb + (size_t)r * CI + ch * 4);
#pragma unroll
            for (int j = 0; j < 4; ++j) Xl[r * XLS + ch * 4 + j] = v[j];
        }
    }
    __syncthreads();

    // ---- B fragments (P^T) for 4 m-quarters x 2 k-halves ----
    // B[k][m]: lane col m = mbase+mq*16+c16, k = kh*32 + h4*8 + j
    bf16x8 bfr[4][2];
#pragma unroll
    for (int mq = 0; mq < 4; ++mq) {
        const int row = mbase + mq * 16 + c16;
#pragma unroll
        for (int kh = 0; kh < 2; ++kh) {
            const int g = ((h4 + 4 * kh) ^ (row & 7)) << 4;
            bfr[mq][kh] = *(const bf16x8*)((const char*)U.p + row * 128 + g);
        }
    }

    // ---- i-loop over this wave's half: 16 steps, next-i prefetch ----
    f32x2 oacc[16] = {};   // [qb*8 + mq*2 + p]: 32 f32
    const char* abase = (const char*)wsG + (size_t)(ih * 16) * 4096
                      + h4 * 256 + c16 * 16;
    const float* xb = &Xl[(mbase + c16) * XLS + ih * 16];  // + mq*16*XLS

    bf16x8 aq[4], an[4];   // [qb*2+kh] current / next
    auto aload = [&](int il, bf16x8* buf) {
        const char* p = abase + (size_t)il * 4096;
        buf[0] = *(const bf16x8*)(p);           // qb0 kh0
        buf[1] = *(const bf16x8*)(p + 1024);    // qb0 kh1
        buf[2] = *(const bf16x8*)(p + 2048);    // qb1 kh0
        buf[3] = *(const bf16x8*)(p + 3072);    // qb1 kh1
    };
    const f32x2 zero2 = {0.0f, 0.0f};
    auto step = [&](const bf16x8* a, int il) {
        f32x2 x2[4];
#pragma unroll
        for (int mq = 0; mq < 4; ++mq) {
            const float x = xb[mq * 16 * XLS + il];
            x2[mq][0] = x; x2[mq][1] = x;
        }
#pragma unroll
        for (int qb = 0; qb < 2; ++qb) {
            f32x4 cc[4] = {};                    // 8 chains of depth 2 per i
#pragma unroll
            for (int mq = 0; mq < 4; ++mq) {
                cc[mq] = __builtin_amdgcn_mfma_f32_16x16x32_bf16(a[qb*2+0], bfr[mq][0], cc[mq], 0, 0, 0);
                cc[mq] = __builtin_amdgcn_mfma_f32_16x16x32_bf16(a[qb*2+1], bfr[mq][1], cc[mq], 0, 0, 0);
            }
#pragma unroll
            for (int mq = 0; mq < 4; ++mq) {
#pragma unroll
                for (int p = 0; p < 2; ++p) {
                    f32x2 pr = {cc[mq][2*p], cc[mq][2*p + 1]};
                    oacc[qb*8 + mq*2 + p] +=
                        __builtin_elementwise_max(pr, zero2) * x2[mq];
                }
            }
        }
    };

    aload(0, aq);
    aload(1, an);
#pragma unroll
    for (int ii = 0; ii < 8; ++ii) {
        step(aq, 2 * ii);
        if (ii < 7) aload(2 * ii + 2, aq);
        step(an, 2 * ii + 1);
        if (ii < 7) aload(2 * ii + 3, an);
    }

    // ---- combine partials: ih=1 publishes, ih=0 adds and stores ----
    __syncthreads();                   // bfr reads long done; U.p -> U.o
    const int ob = (rg * 64 + l) * OLS;
    if (ih == 1) {
#pragma unroll
        for (int r = 0; r < 16; ++r)
            *(f32x2*)&U.o[ob + 2*r] = oacc[r];
    }
    __syncthreads();
    if (ih == 0) {
#pragma unroll
        for (int r = 0; r < 16; ++r)
            oacc[r] += *(const f32x2*)&U.o[ob + 2*r];
        // direct stores: lane (h4,c16): row m = mbase+mq*16+c16, col qb*16+h4*4
#pragma unroll
        for (int qb = 0; qb < 2; ++qb) {
#pragma unroll
            for (int mq = 0; mq < 4; ++mq) {
                f32x4 v;
                v[0] = oacc[qb*8 + mq*2 + 0][0];
                v[1] = oacc[qb*8 + mq*2 + 0][1];
                v[2] = oacc[qb*8 + mq*2 + 1][0];
                v[3] = oacc[qb*8 + mq*2 + 1][1];
                float* orow = outg + (size_t)(tile0 + mbase + mq*16 + c16) * CO
                            + qb * 16 + h4 * 4;
                *(f32x4*)orow = v;
            }
        }
    }
}

extern "C" void kernel_launch(void* const* d_in, const int* in_sizes, int n_in,
                              void* d_out, int out_size, void* d_ws, size_t ws_size,
                              hipStream_t stream)
{
    const float* X  = (const float*)d_in[0];
    const float* P  = (const float*)d_in[1];
    const float* Wk = (const float*)d_in[2];
    float* out  = (float*)d_out;
    __bf16* wsG = (__bf16*)d_ws;   // 32*4096 B = 128 KB

    wk_pack16<<<dim3(CI), dim3(256), 0, stream>>>(Wk, wsG);
    cond_dense_kernel<<<dim3(NBLK), dim3(WG_THREADS), 0, stream>>>(X, P, wsG, out);
}